// Round 7
// baseline (304.647 us; speedup 1.0000x reference)
//
#include <hip/hip_runtime.h>

#define N_NODES 50000
#define IN_CH 128
#define HID 64
#define HID2 32

constexpr int NB2 = 782;     // buckets of 64 nodes: ceil(50000/64)
constexpr int CHUNK = 4096;  // edges per binning block
constexpr int CAP2 = 2560;   // window per bucket (mean 2048, sigma ~45 -> +11 sigma)
#define FPSCALE 524288.0f    // 2^19 fixed-point scale folded into bf16 tables
#define FPINV   0x1p-19f

__device__ __forceinline__ unsigned short f2bf(float f) {
    union { float f; unsigned u; } v; v.f = f;
    unsigned r = v.u + 0x7fff + ((v.u >> 16) & 1);  // RNE
    return (unsigned short)(r >> 16);
}
__device__ __forceinline__ float bflo(unsigned d) {
    union { unsigned u; float f; } v; v.u = d << 16; return v.f;
}
__device__ __forceinline__ float bfhi(unsigned d) {
    union { unsigned u; float f; } v; v.u = d & 0xffff0000u; return v.f;
}

// ---- A: bin edges into fixed per-bucket windows; win = (src<<6)|dstlow ----
__global__ __launch_bounds__(256) void bin_kernel(const int* __restrict__ src,
                                                  const int* __restrict__ dst,
                                                  int* __restrict__ bcur,
                                                  unsigned* __restrict__ win, int E) {
    __shared__ int hist[NB2], lbase[NB2], gbase[NB2], lcur[NB2];  // 12.5 KB
    __shared__ unsigned outp[CHUNK];                              // 16 KB
    int tid = threadIdx.x;
    int base = blockIdx.x * CHUNK;
    int cnt = min(CHUNK, E - base);
    for (int i = tid; i < NB2; i += 256) hist[i] = 0;
    int es[16], ed[16];
    __syncthreads();
#pragma unroll
    for (int k = 0; k < 16; k++) {
        int e = base + k * 256 + tid;
        if (e < E) {
            es[k] = src[e];
            ed[k] = dst[e];
            atomicAdd(&hist[ed[k] >> 6], 1);
        }
    }
    __syncthreads();
    if (tid == 0) {
        int run = 0;
        for (int b = 0; b < NB2; b++) { int t = hist[b]; lbase[b] = run; run += t; }
    }
    __syncthreads();
    for (int i = tid; i < NB2; i += 256) {
        gbase[i] = i * CAP2 + (hist[i] ? atomicAdd(&bcur[i], hist[i]) : 0);
        lcur[i] = lbase[i];
    }
    __syncthreads();
#pragma unroll
    for (int k = 0; k < 16; k++) {
        int e = base + k * 256 + tid;
        if (e < E) {
            int b = ed[k] >> 6;
            int p = atomicAdd(&lcur[b], 1);
            outp[p] = ((unsigned)es[k] << 16) | (unsigned)ed[k];  // dst < 65536
        }
    }
    __syncthreads();
#pragma unroll
    for (int k = 0; k < 16; k++) {
        int i = k * 256 + tid;
        if (i < cnt) {
            unsigned p = outp[i];
            int d = (int)(p & 0xffffu);
            int b = d >> 6;
            win[gbase[b] + (i - lbase[b])] = ((p >> 16) << 6) | (unsigned)(d & 63);
        }
    }
}

// ---- B: per-bucket degree histogram -> dinv ----
__global__ __launch_bounds__(256) void dinv_kernel(const unsigned* __restrict__ win,
                                                   const int* __restrict__ bcur,
                                                   float* __restrict__ dinv, int N) {
    __shared__ int fh[64];
    int b = blockIdx.x, tid = threadIdx.x;
    int cnt = min(bcur[b], CAP2);
    if (tid < 64) fh[tid] = 0;
    __syncthreads();
    for (int i = tid; i < cnt; i += 256) atomicAdd(&fh[win[(size_t)b * CAP2 + i] & 63], 1);
    __syncthreads();
    if (tid < 64) {
        int node = b * 64 + tid;
        if (node < N) dinv[node] = rsqrtf((float)fh[tid] + 1.0f);
    }
}

// ---- GEMM: out_bf16[n][j] = bf16(dinv[n]*2^19*(X@W)[n][j]); K-split transposed LDS ----
template <int K, int J, int NPB>
__global__ __launch_bounds__(256) void gemm_t_kernel(const float* __restrict__ X,
                                                     const float* __restrict__ W,
                                                     const float* __restrict__ dinv,
                                                     unsigned short* __restrict__ out, int N) {
    constexpr int QJ = J / 4, GR = 256 / QJ, NPT = NPB / GR, S = NPB + 4, KC = 64;
    static_assert(NPT == 4, "float4 x-read assumes NPT==4");
    static_assert(K % KC == 0, "");
    __shared__ float Ws[K * J];       // 32 KB / 8 KB
    __shared__ float Xs[KC * S];      // 17.4 KB / 33.8 KB (transposed, stride S)
    int tid = threadIdx.x;
    for (int i = tid; i < K * J / 4; i += 256) ((float4*)Ws)[i] = ((const float4*)W)[i];
    int n0 = blockIdx.x * NPB;
    int q = tid % QJ, g = (tid / QJ) * NPT;
    float4 acc[NPT];
#pragma unroll
    for (int t = 0; t < NPT; t++) acc[t] = make_float4(0.f, 0.f, 0.f, 0.f);
    for (int h = 0; h < K; h += KC) {
        __syncthreads();
        for (int i = tid; i < NPB * KC; i += 256) {
            int kl = i & (KC - 1), r = i >> 6;  // coalesced global read, 8-way LDS write ok
            int n = n0 + r;
            Xs[kl * S + r] = (n < N) ? X[(size_t)n * K + h + kl] : 0.f;
        }
        __syncthreads();
#pragma unroll 8
        for (int kl = 0; kl < KC; kl++) {
            float4 w  = *(const float4*)&Ws[(h + kl) * J + q * 4];
            float4 xv = *(const float4*)&Xs[kl * S + g];
            acc[0].x += xv.x * w.x; acc[0].y += xv.x * w.y; acc[0].z += xv.x * w.z; acc[0].w += xv.x * w.w;
            acc[1].x += xv.y * w.x; acc[1].y += xv.y * w.y; acc[1].z += xv.y * w.z; acc[1].w += xv.y * w.w;
            acc[2].x += xv.z * w.x; acc[2].y += xv.z * w.y; acc[2].z += xv.z * w.z; acc[2].w += xv.z * w.w;
            acc[3].x += xv.w * w.x; acc[3].y += xv.w * w.y; acc[3].z += xv.w * w.z; acc[3].w += xv.w * w.w;
        }
    }
#pragma unroll
    for (int t = 0; t < NPT; t++) {
        int n = n0 + g + t;
        if (n < N) {
            float d0 = dinv[n] * FPSCALE;
            ushort4 o = make_ushort4(f2bf(acc[t].x * d0), f2bf(acc[t].y * d0),
                                     f2bf(acc[t].z * d0), f2bf(acc[t].w * d0));
            *(ushort4*)(out + (size_t)n * J + q * 4) = o;
        }
    }
}

// ---- layer-1 aggregate: one block per 64-node bucket, LDS int32 accumulators ----
__global__ __launch_bounds__(256) void bucket_agg1_kernel(const unsigned* __restrict__ win,
                                                          const int* __restrict__ bcur,
                                                          const float* __restrict__ dinv,
                                                          const unsigned short* __restrict__ xws,
                                                          const float* __restrict__ b1,
                                                          float* __restrict__ h1, int N) {
    __shared__ int acc[64 * 65];       // 16.6 KB, stride 65 (bank-spread)
    __shared__ unsigned lwin[CAP2];    // 10 KB
    int b = blockIdx.x, tid = threadIdx.x;
    size_t base = (size_t)b * CAP2;
    int cnt = min(bcur[b], CAP2);
    for (int i = tid; i < 64 * 65; i += 256) acc[i] = 0;
    for (int i = tid; i < cnt; i += 256) lwin[i] = win[base + i];
    __syncthreads();
    const unsigned* xw_u = (const unsigned*)xws;  // 32 uints (2 bf16 each) per node
    int grp = tid >> 5, fp = tid & 31;            // 8 edge-groups x 32 featpair-lanes
    for (int e = grp; e < cnt; e += 8) {
        unsigned p = lwin[e];
        int s = (int)(p >> 6), dl = (int)(p & 63);
        unsigned q = xw_u[(size_t)s * 32 + fp];
        atomicAdd(&acc[dl * 65 + fp * 2],     (int)bflo(q));
        atomicAdd(&acc[dl * 65 + fp * 2 + 1], (int)bfhi(q));
    }
    __syncthreads();
    // epilogue: 4 threads per node, 16 feats each
    int nl = tid >> 2, seg = (tid & 3) * 16;
    int node = b * 64 + nl;
    if (node < N) {
        float dis = dinv[node] * FPINV;
        float o[16];
#pragma unroll
        for (int j = 0; j < 8; j++) {
            unsigned q = xw_u[(size_t)node * 32 + (seg >> 1) + j];  // self-loop term
            int a0 = acc[nl * 65 + seg + 2 * j]     + (int)bflo(q);
            int a1 = acc[nl * 65 + seg + 2 * j + 1] + (int)bfhi(q);
            o[2 * j]     = fmaxf((float)a0 * dis + b1[seg + 2 * j], 0.f);
            o[2 * j + 1] = fmaxf((float)a1 * dis + b1[seg + 2 * j + 1], 0.f);
        }
        float4* d4 = (float4*)(h1 + (size_t)node * HID + seg);
        d4[0] = make_float4(o[0], o[1], o[2], o[3]);
        d4[1] = make_float4(o[4], o[5], o[6], o[7]);
        d4[2] = make_float4(o[8], o[9], o[10], o[11]);
        d4[3] = make_float4(o[12], o[13], o[14], o[15]);
    }
}

// ---- layer-2 aggregate + head: one block per bucket ----
__global__ __launch_bounds__(256) void bucket_agg2_kernel(const unsigned* __restrict__ win,
                                                          const int* __restrict__ bcur,
                                                          const float* __restrict__ dinv,
                                                          const unsigned short* __restrict__ hws,
                                                          const float* __restrict__ b2,
                                                          const float* __restrict__ Wh,
                                                          const float* __restrict__ bh,
                                                          float* __restrict__ out, int N) {
    __shared__ int acc[64 * 33];       // 8.4 KB
    __shared__ unsigned lwin[CAP2];    // 10 KB
    int b = blockIdx.x, tid = threadIdx.x;
    size_t base = (size_t)b * CAP2;
    int cnt = min(bcur[b], CAP2);
    for (int i = tid; i < 64 * 33; i += 256) acc[i] = 0;
    for (int i = tid; i < cnt; i += 256) lwin[i] = win[base + i];
    __syncthreads();
    const unsigned* hw_u = (const unsigned*)hws;  // 16 uints per node
    int grp = tid >> 4, fp = tid & 15;            // 16 edge-groups x 16 featpair-lanes
    for (int e = grp; e < cnt; e += 16) {
        unsigned p = lwin[e];
        int s = (int)(p >> 6), dl = (int)(p & 63);
        unsigned q = hw_u[(size_t)s * 16 + fp];
        atomicAdd(&acc[dl * 33 + fp * 2],     (int)bflo(q));
        atomicAdd(&acc[dl * 33 + fp * 2 + 1], (int)bfhi(q));
    }
    __syncthreads();
    if (tid < 64) {
        int node = b * 64 + tid;
        if (node < N) {
            float dis = dinv[node] * FPINV;
            float pacc = 0.f;
#pragma unroll
            for (int j = 0; j < 16; j++) {
                unsigned q = hw_u[(size_t)node * 16 + j];  // self-loop
                int a0 = acc[tid * 33 + 2 * j]     + (int)bflo(q);
                int a1 = acc[tid * 33 + 2 * j + 1] + (int)bfhi(q);
                pacc += fmaxf((float)a0 * dis + b2[2 * j], 0.f) * Wh[2 * j];
                pacc += fmaxf((float)a1 * dis + b2[2 * j + 1], 0.f) * Wh[2 * j + 1];
            }
            out[node] = pacc + bh[0];
        }
    }
}

extern "C" void kernel_launch(void* const* d_in, const int* in_sizes, int n_in,
                              void* d_out, int out_size, void* d_ws, size_t ws_size,
                              hipStream_t stream) {
    const float* x  = (const float*)d_in[0];
    const int*   ei = (const int*)d_in[1];
    const float* W1 = (const float*)d_in[2];
    const float* b1 = (const float*)d_in[3];
    const float* W2 = (const float*)d_in[4];
    const float* b2 = (const float*)d_in[5];
    const float* Wh = (const float*)d_in[6];
    const float* bh = (const float*)d_in[7];
    float* out = (float*)d_out;

    const int N = N_NODES;
    const int E = in_sizes[1] / 2;
    const int* src = ei;
    const int* dst = ei + E;

    // workspace layout (~27.4 MB)
    int* ws = (int*)d_ws;
    int*            bcur = ws;                                    // 1024 ints
    float*          dinv = (float*)(ws + 1024);                   // 50048 floats
    unsigned*       win  = (unsigned*)(dinv + 50048);             // NB2*CAP2 (8 MB)
    unsigned short* xws  = (unsigned short*)(win + (size_t)NB2 * CAP2);  // N*64 bf16 (6.4 MB)
    float*          h1   = (float*)(xws + (size_t)N * HID);       // N*64 f32 (12.8 MB)
    unsigned short* hws  = xws;                                   // alias: xws dead after agg1

    hipMemsetAsync(bcur, 0, NB2 * sizeof(int), stream);

    int eblocks = (E + CHUNK - 1) / CHUNK;
    bin_kernel<<<eblocks, 256, 0, stream>>>(src, dst, bcur, win, E);
    dinv_kernel<<<NB2, 256, 0, stream>>>(win, bcur, dinv, N);

    // layer 1
    gemm_t_kernel<IN_CH, HID, 64><<<(N + 63) / 64, 256, 0, stream>>>(x, W1, dinv, xws, N);
    bucket_agg1_kernel<<<NB2, 256, 0, stream>>>(win, bcur, dinv, xws, b1, h1, N);

    // layer 2 + head
    gemm_t_kernel<HID, HID2, 128><<<(N + 127) / 128, 256, 0, stream>>>(h1, W2, dinv, hws, N);
    bucket_agg2_kernel<<<NB2, 256, 0, stream>>>(win, bcur, dinv, hws, b2, Wh, bh, out, N);
}

// Round 8
// 231.310 us; speedup vs baseline: 1.3171x; 1.3171x over previous
//
#include <hip/hip_runtime.h>

#define N_NODES 50000
#define IN_CH 128
#define HID 64
#define HID2 32

constexpr int NB = 391;      // coarse buckets of 128 nodes: ceil(50000/128)
constexpr int CHUNK = 4096;  // edges per binning block
constexpr int CAP = 5120;    // fixed window per bucket (mean 4096, +16 sigma)
#define FPSCALE 524288.0f    // 2^19 fixed-point scale folded into bf16 tables
#define FPINV   0x1p-19f

__device__ __forceinline__ unsigned short f2bf(float f) {
    union { float f; unsigned u; } v; v.f = f;
    unsigned r = v.u + 0x7fff + ((v.u >> 16) & 1);  // RNE
    return (unsigned short)(r >> 16);
}
__device__ __forceinline__ float bflo(unsigned d) {
    union { unsigned u; float f; } v; v.u = d << 16; return v.f;
}
__device__ __forceinline__ float bfhi(unsigned d) {
    union { unsigned u; float f; } v; v.u = d & 0xffff0000u; return v.f;
}

// ---- A: bin edges into fixed per-bucket windows (bucket-grouped writes) ----
__global__ __launch_bounds__(256) void bin_kernel(const int* __restrict__ src,
                                                  const int* __restrict__ dst,
                                                  int* __restrict__ bcur,
                                                  unsigned short* __restrict__ psrc,
                                                  unsigned char* __restrict__ pbyte, int E) {
    __shared__ int hist[NB], lbase[NB], gbase[NB], lcur[NB];
    __shared__ unsigned short outs[CHUNK];
    __shared__ int outd[CHUNK];
    int tid = threadIdx.x;
    int base = blockIdx.x * CHUNK;
    int cnt = min(CHUNK, E - base);
    for (int i = tid; i < NB; i += 256) hist[i] = 0;
    int es[CHUNK / 256], ed[CHUNK / 256];
    __syncthreads();
#pragma unroll
    for (int k = 0; k < CHUNK / 256; k++) {
        int e = base + k * 256 + tid;
        if (e < E) {
            es[k] = src[e];
            ed[k] = dst[e];
            atomicAdd(&hist[ed[k] >> 7], 1);
        }
    }
    __syncthreads();
    if (tid == 0) {
        int run = 0;
        for (int b = 0; b < NB; b++) { int t = hist[b]; lbase[b] = run; run += t; }
    }
    __syncthreads();
    for (int i = tid; i < NB; i += 256) {
        gbase[i] = i * CAP + (hist[i] ? atomicAdd(&bcur[i], hist[i]) : 0);
        lcur[i] = lbase[i];
    }
    __syncthreads();
#pragma unroll
    for (int k = 0; k < CHUNK / 256; k++) {
        int e = base + k * 256 + tid;
        if (e < E) {
            int b = ed[k] >> 7;
            int p = atomicAdd(&lcur[b], 1);
            outs[p] = (unsigned short)es[k];
            outd[p] = ed[k];
        }
    }
    __syncthreads();
#pragma unroll
    for (int k = 0; k < CHUNK / 256; k++) {
        int i = k * 256 + tid;
        if (i < cnt) {
            int d = outd[i];
            int b = d >> 7;
            int gp = gbase[b] + (i - lbase[b]);
            psrc[gp] = outs[i];
            pbyte[gp] = (unsigned char)(d & 127);
        }
    }
}

// ---- B: per-bucket fine pass: group window by node (order-free; sums are int).
//      Emits CSR-in-window psrc, off, len, dinv. ----
__global__ __launch_bounds__(256) void fine_kernel(unsigned short* __restrict__ psrc,
                                                   const unsigned char* __restrict__ pbyte,
                                                   const int* __restrict__ bcur,
                                                   int* __restrict__ off,
                                                   unsigned short* __restrict__ len,
                                                   float* __restrict__ dinv, int N) {
    __shared__ unsigned short lsrc[CAP];
    __shared__ unsigned char lb[CAP];
    __shared__ int fh[128], fb[128], fc[128];
    int b = blockIdx.x, tid = threadIdx.x;
    int gb = b * CAP;
    int cnt = min(bcur[b], CAP);
    if (tid < 128) fh[tid] = 0;
    __syncthreads();
    for (int i = tid; i < cnt; i += 256) {
        lsrc[i] = psrc[gb + i];
        int dl = pbyte[gb + i];
        lb[i] = (unsigned char)dl;
        atomicAdd(&fh[dl], 1);
    }
    __syncthreads();
    if (tid == 0) {
        int run = 0;
        for (int j = 0; j < 128; j++) { int t = fh[j]; fb[j] = run; run += t; }
    }
    __syncthreads();
    if (tid < 128) {
        fc[tid] = fb[tid];
        int node = (b << 7) + tid;
        if (node < N) {
            off[node] = gb + fb[tid];
            len[node] = (unsigned short)fh[tid];
            dinv[node] = rsqrtf((float)fh[tid] + 1.0f);
        }
    }
    __syncthreads();
    for (int i = tid; i < cnt; i += 256) {
        int p = atomicAdd(&fc[lb[i]], 1);
        psrc[gb + p] = lsrc[i];
    }
}

// ---- GEMM: out_bf16[n][j] = bf16(dinv[n]*2^19*(X@W)[n][j]); K-split transposed LDS ----
template <int K, int J, int NPB>
__global__ __launch_bounds__(256) void gemm_t_kernel(const float* __restrict__ X,
                                                     const float* __restrict__ W,
                                                     const float* __restrict__ dinv,
                                                     unsigned short* __restrict__ out, int N) {
    constexpr int QJ = J / 4, GR = 256 / QJ, NPT = NPB / GR, S = NPB + 4, KC = 64;
    static_assert(NPT == 4, "float4 x-read assumes NPT==4");
    static_assert(K % KC == 0, "");
    __shared__ float Ws[K * J];
    __shared__ float Xs[KC * S];
    int tid = threadIdx.x;
    for (int i = tid; i < K * J / 4; i += 256) ((float4*)Ws)[i] = ((const float4*)W)[i];
    int n0 = blockIdx.x * NPB;
    int q = tid % QJ, g = (tid / QJ) * NPT;
    float4 acc[NPT];
#pragma unroll
    for (int t = 0; t < NPT; t++) acc[t] = make_float4(0.f, 0.f, 0.f, 0.f);
    for (int h = 0; h < K; h += KC) {
        __syncthreads();
        for (int i = tid; i < NPB * KC; i += 256) {
            int kl = i & (KC - 1), r = i >> 6;  // coalesced global read along K
            int n = n0 + r;
            Xs[kl * S + r] = (n < N) ? X[(size_t)n * K + h + kl] : 0.f;
        }
        __syncthreads();
#pragma unroll 8
        for (int kl = 0; kl < KC; kl++) {
            float4 w  = *(const float4*)&Ws[(h + kl) * J + q * 4];
            float4 xv = *(const float4*)&Xs[kl * S + g];
            acc[0].x += xv.x * w.x; acc[0].y += xv.x * w.y; acc[0].z += xv.x * w.z; acc[0].w += xv.x * w.w;
            acc[1].x += xv.y * w.x; acc[1].y += xv.y * w.y; acc[1].z += xv.y * w.z; acc[1].w += xv.y * w.w;
            acc[2].x += xv.z * w.x; acc[2].y += xv.z * w.y; acc[2].z += xv.z * w.z; acc[2].w += xv.z * w.w;
            acc[3].x += xv.w * w.x; acc[3].y += xv.w * w.y; acc[3].z += xv.w * w.z; acc[3].w += xv.w * w.w;
        }
    }
#pragma unroll
    for (int t = 0; t < NPT; t++) {
        int n = n0 + g + t;
        if (n < N) {
            float d0 = dinv[n] * FPSCALE;
            ushort4 o = make_ushort4(f2bf(acc[t].x * d0), f2bf(acc[t].y * d0),
                                     f2bf(acc[t].z * d0), f2bf(acc[t].w * d0));
            *(ushort4*)(out + (size_t)n * J + q * 4) = o;
        }
    }
}

// ---- layer-1 aggregate: wave/node, F=64, bf16 table, int32 fixed-point sums --
__global__ __launch_bounds__(256) void agg1_kernel(const unsigned short* __restrict__ sorted_src,
                                                   const int* __restrict__ off,
                                                   const unsigned short* __restrict__ len,
                                                   const float* __restrict__ dinv,
                                                   const unsigned short* __restrict__ xws,
                                                   const float* __restrict__ b1,
                                                   float* __restrict__ h1, int N) {
    int lane = threadIdx.x & 63;
    int n = blockIdx.x * 4 + (threadIdx.x >> 6);
    if (n >= N) return;
    int g = lane >> 3, fl = lane & 7;  // 8 edge-groups x 8 feature-lanes
    int start = off[n], end = start + len[n];
    int acc[8] = {0, 0, 0, 0, 0, 0, 0, 0};
    int i = start + g;
    for (; i + 8 < end; i += 16) {  // 2-way unroll: two gathers in flight
        int s0 = sorted_src[i], s1 = sorted_src[i + 8];
        uint4 q0 = *(const uint4*)(xws + (size_t)s0 * HID + fl * 8);
        uint4 q1 = *(const uint4*)(xws + (size_t)s1 * HID + fl * 8);
        acc[0] += (int)bflo(q0.x) + (int)bflo(q1.x);
        acc[1] += (int)bfhi(q0.x) + (int)bfhi(q1.x);
        acc[2] += (int)bflo(q0.y) + (int)bflo(q1.y);
        acc[3] += (int)bfhi(q0.y) + (int)bfhi(q1.y);
        acc[4] += (int)bflo(q0.z) + (int)bflo(q1.z);
        acc[5] += (int)bfhi(q0.z) + (int)bfhi(q1.z);
        acc[6] += (int)bflo(q0.w) + (int)bflo(q1.w);
        acc[7] += (int)bfhi(q0.w) + (int)bfhi(q1.w);
    }
    if (i < end) {
        int s = sorted_src[i];
        uint4 q = *(const uint4*)(xws + (size_t)s * HID + fl * 8);
        acc[0] += (int)bflo(q.x); acc[1] += (int)bfhi(q.x);
        acc[2] += (int)bflo(q.y); acc[3] += (int)bfhi(q.y);
        acc[4] += (int)bflo(q.z); acc[5] += (int)bfhi(q.z);
        acc[6] += (int)bflo(q.w); acc[7] += (int)bfhi(q.w);
    }
#pragma unroll
    for (int m = 8; m <= 32; m <<= 1)
#pragma unroll
        for (int j = 0; j < 8; j++) acc[j] += __shfl_xor(acc[j], m, 64);
    if (g == 0) {
        float dis = dinv[n] * FPINV;
        uint4 q = *(const uint4*)(xws + (size_t)n * HID + fl * 8);
        int sv[8] = {(int)bflo(q.x), (int)bfhi(q.x), (int)bflo(q.y), (int)bfhi(q.y),
                     (int)bflo(q.z), (int)bfhi(q.z), (int)bflo(q.w), (int)bfhi(q.w)};
        float4 bb0 = *(const float4*)(b1 + fl * 8);
        float4 bb1 = *(const float4*)(b1 + fl * 8 + 4);
        float bbv[8] = {bb0.x, bb0.y, bb0.z, bb0.w, bb1.x, bb1.y, bb1.z, bb1.w};
        float o[8];
#pragma unroll
        for (int j = 0; j < 8; j++)
            o[j] = fmaxf((float)(acc[j] + sv[j]) * dis + bbv[j], 0.f);
        *(float4*)(h1 + (size_t)n * HID + fl * 8)     = make_float4(o[0], o[1], o[2], o[3]);
        *(float4*)(h1 + (size_t)n * HID + fl * 8 + 4) = make_float4(o[4], o[5], o[6], o[7]);
    }
}

// ---- layer-2 aggregate + head: wave/node, F=32, bf16 table, int32 sums -------
__global__ __launch_bounds__(256) void agg2_final_kernel(const unsigned short* __restrict__ sorted_src,
                                                         const int* __restrict__ off,
                                                         const unsigned short* __restrict__ len,
                                                         const float* __restrict__ dinv,
                                                         const unsigned short* __restrict__ hws,
                                                         const float* __restrict__ b2,
                                                         const float* __restrict__ Wh,
                                                         const float* __restrict__ bh,
                                                         float* __restrict__ out, int N) {
    int lane = threadIdx.x & 63;
    int n = blockIdx.x * 4 + (threadIdx.x >> 6);
    if (n >= N) return;
    int g = lane >> 2, fl = lane & 3;  // 16 edge-groups x 4 feature-lanes
    int start = off[n], end = start + len[n];
    int acc[8] = {0, 0, 0, 0, 0, 0, 0, 0};
    int i = start + g;
    for (; i + 16 < end; i += 32) {  // 2-way unroll
        int s0 = sorted_src[i], s1 = sorted_src[i + 16];
        uint4 q0 = *(const uint4*)(hws + (size_t)s0 * HID2 + fl * 8);
        uint4 q1 = *(const uint4*)(hws + (size_t)s1 * HID2 + fl * 8);
        acc[0] += (int)bflo(q0.x) + (int)bflo(q1.x);
        acc[1] += (int)bfhi(q0.x) + (int)bfhi(q1.x);
        acc[2] += (int)bflo(q0.y) + (int)bflo(q1.y);
        acc[3] += (int)bfhi(q0.y) + (int)bfhi(q1.y);
        acc[4] += (int)bflo(q0.z) + (int)bflo(q1.z);
        acc[5] += (int)bfhi(q0.z) + (int)bfhi(q1.z);
        acc[6] += (int)bflo(q0.w) + (int)bflo(q1.w);
        acc[7] += (int)bfhi(q0.w) + (int)bfhi(q1.w);
    }
    if (i < end) {
        int s = sorted_src[i];
        uint4 q = *(const uint4*)(hws + (size_t)s * HID2 + fl * 8);
        acc[0] += (int)bflo(q.x); acc[1] += (int)bfhi(q.x);
        acc[2] += (int)bflo(q.y); acc[3] += (int)bfhi(q.y);
        acc[4] += (int)bflo(q.z); acc[5] += (int)bfhi(q.z);
        acc[6] += (int)bflo(q.w); acc[7] += (int)bfhi(q.w);
    }
#pragma unroll
    for (int m = 4; m <= 32; m <<= 1)
#pragma unroll
        for (int j = 0; j < 8; j++) acc[j] += __shfl_xor(acc[j], m, 64);
    float dis = dinv[n] * FPINV;
    uint4 q = *(const uint4*)(hws + (size_t)n * HID2 + fl * 8);
    int sv[8] = {(int)bflo(q.x), (int)bfhi(q.x), (int)bflo(q.y), (int)bfhi(q.y),
                 (int)bflo(q.z), (int)bfhi(q.z), (int)bflo(q.w), (int)bfhi(q.w)};
    float4 bb0 = *(const float4*)(b2 + fl * 8);
    float4 bb1 = *(const float4*)(b2 + fl * 8 + 4);
    float bbv[8] = {bb0.x, bb0.y, bb0.z, bb0.w, bb1.x, bb1.y, bb1.z, bb1.w};
    float4 wv0 = *(const float4*)(Wh + fl * 8);
    float4 wv1 = *(const float4*)(Wh + fl * 8 + 4);
    float wvv[8] = {wv0.x, wv0.y, wv0.z, wv0.w, wv1.x, wv1.y, wv1.z, wv1.w};
    float p = 0.f;
#pragma unroll
    for (int j = 0; j < 8; j++)
        p += fmaxf((float)(acc[j] + sv[j]) * dis + bbv[j], 0.f) * wvv[j];
    p += __shfl_xor(p, 1, 64);
    p += __shfl_xor(p, 2, 64);
    if (lane == 0) out[n] = p + bh[0];
}

extern "C" void kernel_launch(void* const* d_in, const int* in_sizes, int n_in,
                              void* d_out, int out_size, void* d_ws, size_t ws_size,
                              hipStream_t stream) {
    const float* x  = (const float*)d_in[0];
    const int*   ei = (const int*)d_in[1];
    const float* W1 = (const float*)d_in[2];
    const float* b1 = (const float*)d_in[3];
    const float* W2 = (const float*)d_in[4];
    const float* b2 = (const float*)d_in[5];
    const float* Wh = (const float*)d_in[6];
    const float* bh = (const float*)d_in[7];
    float* out = (float*)d_out;

    const int N = N_NODES;
    const int E = in_sizes[1] / 2;
    const int* src = ei;
    const int* dst = ei + E;

    // workspace layout
    int* ws = (int*)d_ws;
    int*            bcur  = ws;                                   // 512 ints
    int*            off   = bcur + 512;                           // 50048 ints
    unsigned short* len   = (unsigned short*)(off + 50048);       // 50048 ushort
    float*          dinv  = (float*)((int*)len + 25024);          // 50048 floats
    unsigned short* psrc  = (unsigned short*)(dinv + 50048);      // NB*CAP ushort (4 MB)
    unsigned char*  pbyte = (unsigned char*)(psrc + (size_t)NB * CAP);  // NB*CAP bytes (2 MB)
    unsigned short* xws   = (unsigned short*)(pbyte + (size_t)NB * CAP);// N*64 bf16 (6.4 MB)
    float*          h1    = (float*)(xws + (size_t)N * HID);      // N*64 f32 (12.8 MB)
    unsigned short* hws   = xws;                                  // alias: xws dead after agg1

    hipMemsetAsync(bcur, 0, NB * sizeof(int), stream);

    int eblocks = (E + CHUNK - 1) / CHUNK;
    bin_kernel<<<eblocks, 256, 0, stream>>>(src, dst, bcur, psrc, pbyte, E);
    fine_kernel<<<NB, 256, 0, stream>>>(psrc, pbyte, bcur, off, len, dinv, N);

    // layer 1
    gemm_t_kernel<IN_CH, HID, 64><<<(N + 63) / 64, 256, 0, stream>>>(x, W1, dinv, xws, N);
    agg1_kernel<<<(N + 3) / 4, 256, 0, stream>>>(psrc, off, len, dinv, xws, b1, h1, N);

    // layer 2 + head
    gemm_t_kernel<HID, HID2, 128><<<(N + 127) / 128, 256, 0, stream>>>(h1, W2, dinv, hws, N);
    agg2_final_kernel<<<(N + 3) / 4, 256, 0, stream>>>(psrc, off, len, dinv, hws, b2, Wh, bh, out, N);
}

// Round 9
// 211.802 us; speedup vs baseline: 1.4384x; 1.0921x over previous
//
#include <hip/hip_runtime.h>

#define N_NODES 50000
#define IN_CH 128
#define HID 64
#define HID2 32

constexpr int NB = 391;      // coarse buckets of 128 nodes: ceil(50000/128)
constexpr int CHUNK = 4096;  // edges per binning block
constexpr int CAP = 5120;    // fixed window per bucket (mean 4096, +16 sigma)
#define FPSCALE 524288.0f    // 2^19 fixed-point scale folded into bf16 tables
#define FPINV   0x1p-19f

__device__ __forceinline__ unsigned short f2bf(float f) {
    union { float f; unsigned u; } v; v.f = f;
    unsigned r = v.u + 0x7fff + ((v.u >> 16) & 1);  // RNE
    return (unsigned short)(r >> 16);
}
__device__ __forceinline__ float bflo(unsigned d) {
    union { unsigned u; float f; } v; v.u = d << 16; return v.f;
}
__device__ __forceinline__ float bfhi(unsigned d) {
    union { unsigned u; float f; } v; v.u = d & 0xffff0000u; return v.f;
}

// ---- A: bin edges into fixed per-bucket windows (bucket-grouped writes) ----
__global__ __launch_bounds__(256) void bin_kernel(const int* __restrict__ src,
                                                  const int* __restrict__ dst,
                                                  int* __restrict__ bcur,
                                                  unsigned short* __restrict__ psrc,
                                                  unsigned char* __restrict__ pbyte, int E) {
    __shared__ int hist[NB], lbase[NB], gbase[NB], lcur[NB];
    __shared__ unsigned short outs[CHUNK];
    __shared__ int outd[CHUNK];
    int tid = threadIdx.x;
    int base = blockIdx.x * CHUNK;
    int cnt = min(CHUNK, E - base);
    for (int i = tid; i < NB; i += 256) hist[i] = 0;
    int es[CHUNK / 256], ed[CHUNK / 256];
    __syncthreads();
#pragma unroll
    for (int k = 0; k < CHUNK / 256; k++) {
        int e = base + k * 256 + tid;
        if (e < E) {
            es[k] = src[e];
            ed[k] = dst[e];
            atomicAdd(&hist[ed[k] >> 7], 1);
        }
    }
    __syncthreads();
    if (tid == 0) {
        int run = 0;
        for (int b = 0; b < NB; b++) { int t = hist[b]; lbase[b] = run; run += t; }
    }
    __syncthreads();
    for (int i = tid; i < NB; i += 256) {
        gbase[i] = i * CAP + (hist[i] ? atomicAdd(&bcur[i], hist[i]) : 0);
        lcur[i] = lbase[i];
    }
    __syncthreads();
#pragma unroll
    for (int k = 0; k < CHUNK / 256; k++) {
        int e = base + k * 256 + tid;
        if (e < E) {
            int b = ed[k] >> 7;
            int p = atomicAdd(&lcur[b], 1);
            outs[p] = (unsigned short)es[k];
            outd[p] = ed[k];
        }
    }
    __syncthreads();
#pragma unroll
    for (int k = 0; k < CHUNK / 256; k++) {
        int i = k * 256 + tid;
        if (i < cnt) {
            int d = outd[i];
            int b = d >> 7;
            int gp = gbase[b] + (i - lbase[b]);
            psrc[gp] = outs[i];
            pbyte[gp] = (unsigned char)(d & 127);
        }
    }
}

// ---- B: per-bucket fine pass: group window by node (order-free; sums are int).
//      Emits CSR-in-window psrc, off, len, dinv. ----
__global__ __launch_bounds__(256) void fine_kernel(unsigned short* __restrict__ psrc,
                                                   const unsigned char* __restrict__ pbyte,
                                                   const int* __restrict__ bcur,
                                                   int* __restrict__ off,
                                                   unsigned short* __restrict__ len,
                                                   float* __restrict__ dinv, int N) {
    __shared__ unsigned short lsrc[CAP];
    __shared__ unsigned char lb[CAP];
    __shared__ int fh[128], fb[128], fc[128];
    int b = blockIdx.x, tid = threadIdx.x;
    int gb = b * CAP;
    int cnt = min(bcur[b], CAP);
    if (tid < 128) fh[tid] = 0;
    __syncthreads();
    for (int i = tid; i < cnt; i += 256) {
        lsrc[i] = psrc[gb + i];
        int dl = pbyte[gb + i];
        lb[i] = (unsigned char)dl;
        atomicAdd(&fh[dl], 1);
    }
    __syncthreads();
    if (tid == 0) {
        int run = 0;
        for (int j = 0; j < 128; j++) { int t = fh[j]; fb[j] = run; run += t; }
    }
    __syncthreads();
    if (tid < 128) {
        fc[tid] = fb[tid];
        int node = (b << 7) + tid;
        if (node < N) {
            off[node] = gb + fb[tid];
            len[node] = (unsigned short)fh[tid];
            dinv[node] = rsqrtf((float)fh[tid] + 1.0f);
        }
    }
    __syncthreads();
    for (int i = tid; i < cnt; i += 256) {
        int p = atomicAdd(&fc[lb[i]], 1);
        psrc[gb + p] = lsrc[i];
    }
}

// ---- GEMM: out_bf16[n][j] = bf16(dinv[n]*2^19*(X@W)[n][j])
//      Single barrier; XOR-swizzled row-major Xs (conflict-free staging);
//      scalar broadcast x-reads in the K-loop. NPT = 2 nodes/thread. ----
template <int K, int J, int NPB>
__global__ __launch_bounds__(256) void gemm_s_kernel(const float* __restrict__ X,
                                                     const float* __restrict__ W,
                                                     const float* __restrict__ dinv,
                                                     unsigned short* __restrict__ out, int N) {
    constexpr int QJ = J / 4;          // 16 (J=64) or 8 (J=32)
    constexpr int NPT = NPB / (256 / QJ);
    static_assert(NPT == 2, "layout assumes 2 nodes/thread");
    constexpr int RG = K / 4;          // float4 granules per row
    constexpr int RS = K + 4;          // row stride (floats)
    __shared__ float Ws[K * J];
    __shared__ float Xs[NPB * RS];
    int tid = threadIdx.x;
    for (int i = tid; i < K * J / 4; i += 256) ((float4*)Ws)[i] = ((const float4*)W)[i];
    int n0 = blockIdx.x * NPB;
    for (int i = tid; i < NPB * RG; i += 256) {
        int r = i / RG, c = i % RG;
        int n = n0 + r;
        float4 v = make_float4(0.f, 0.f, 0.f, 0.f);
        if (n < N) v = ((const float4*)(X + (size_t)n * K))[c];
        *(float4*)&Xs[r * RS + ((c ^ (r & 7)) << 2)] = v;
    }
    __syncthreads();
    int q = tid % QJ, g = (tid / QJ) * NPT;
    const float* xr0 = &Xs[g * RS];
    const float* xr1 = &Xs[(g + 1) * RS];
    int sw0 = g & 7, sw1 = (g + 1) & 7;
    float4 a0 = make_float4(0.f, 0.f, 0.f, 0.f);
    float4 a1 = make_float4(0.f, 0.f, 0.f, 0.f);
#pragma unroll 8
    for (int k = 0; k < K; k++) {
        float4 w = *(const float4*)&Ws[k * J + q * 4];
        float x0 = xr0[(((k >> 2) ^ sw0) << 2) + (k & 3)];
        float x1 = xr1[(((k >> 2) ^ sw1) << 2) + (k & 3)];
        a0.x += x0 * w.x; a0.y += x0 * w.y; a0.z += x0 * w.z; a0.w += x0 * w.w;
        a1.x += x1 * w.x; a1.y += x1 * w.y; a1.z += x1 * w.z; a1.w += x1 * w.w;
    }
    int n = n0 + g;
    if (n < N) {
        float d0 = dinv[n] * FPSCALE;
        ushort4 o = make_ushort4(f2bf(a0.x * d0), f2bf(a0.y * d0),
                                 f2bf(a0.z * d0), f2bf(a0.w * d0));
        *(ushort4*)(out + (size_t)n * J + q * 4) = o;
    }
    if (n + 1 < N) {
        float d1 = dinv[n + 1] * FPSCALE;
        ushort4 o = make_ushort4(f2bf(a1.x * d1), f2bf(a1.y * d1),
                                 f2bf(a1.z * d1), f2bf(a1.w * d1));
        *(ushort4*)(out + (size_t)(n + 1) * J + q * 4) = o;
    }
}

// ---- layer-1 aggregate: wave/node, F=64, bf16 table, int32 fixed-point sums --
__global__ __launch_bounds__(256) void agg1_kernel(const unsigned short* __restrict__ sorted_src,
                                                   const int* __restrict__ off,
                                                   const unsigned short* __restrict__ len,
                                                   const float* __restrict__ dinv,
                                                   const unsigned short* __restrict__ xws,
                                                   const float* __restrict__ b1,
                                                   float* __restrict__ h1, int N) {
    int lane = threadIdx.x & 63;
    int n = blockIdx.x * 4 + (threadIdx.x >> 6);
    if (n >= N) return;
    int g = lane >> 3, fl = lane & 7;  // 8 edge-groups x 8 feature-lanes
    int start = off[n], end = start + len[n];
    int acc[8] = {0, 0, 0, 0, 0, 0, 0, 0};
    int i = start + g;
    for (; i + 8 < end; i += 16) {  // 2-way unroll: two gathers in flight
        int s0 = sorted_src[i], s1 = sorted_src[i + 8];
        uint4 q0 = *(const uint4*)(xws + (size_t)s0 * HID + fl * 8);
        uint4 q1 = *(const uint4*)(xws + (size_t)s1 * HID + fl * 8);
        acc[0] += (int)bflo(q0.x) + (int)bflo(q1.x);
        acc[1] += (int)bfhi(q0.x) + (int)bfhi(q1.x);
        acc[2] += (int)bflo(q0.y) + (int)bflo(q1.y);
        acc[3] += (int)bfhi(q0.y) + (int)bfhi(q1.y);
        acc[4] += (int)bflo(q0.z) + (int)bflo(q1.z);
        acc[5] += (int)bfhi(q0.z) + (int)bfhi(q1.z);
        acc[6] += (int)bflo(q0.w) + (int)bflo(q1.w);
        acc[7] += (int)bfhi(q0.w) + (int)bfhi(q1.w);
    }
    if (i < end) {
        int s = sorted_src[i];
        uint4 q = *(const uint4*)(xws + (size_t)s * HID + fl * 8);
        acc[0] += (int)bflo(q.x); acc[1] += (int)bfhi(q.x);
        acc[2] += (int)bflo(q.y); acc[3] += (int)bfhi(q.y);
        acc[4] += (int)bflo(q.z); acc[5] += (int)bfhi(q.z);
        acc[6] += (int)bflo(q.w); acc[7] += (int)bfhi(q.w);
    }
#pragma unroll
    for (int m = 8; m <= 32; m <<= 1)
#pragma unroll
        for (int j = 0; j < 8; j++) acc[j] += __shfl_xor(acc[j], m, 64);
    if (g == 0) {
        float dis = dinv[n] * FPINV;
        uint4 q = *(const uint4*)(xws + (size_t)n * HID + fl * 8);
        int sv[8] = {(int)bflo(q.x), (int)bfhi(q.x), (int)bflo(q.y), (int)bfhi(q.y),
                     (int)bflo(q.z), (int)bfhi(q.z), (int)bflo(q.w), (int)bfhi(q.w)};
        float4 bb0 = *(const float4*)(b1 + fl * 8);
        float4 bb1 = *(const float4*)(b1 + fl * 8 + 4);
        float bbv[8] = {bb0.x, bb0.y, bb0.z, bb0.w, bb1.x, bb1.y, bb1.z, bb1.w};
        float o[8];
#pragma unroll
        for (int j = 0; j < 8; j++)
            o[j] = fmaxf((float)(acc[j] + sv[j]) * dis + bbv[j], 0.f);
        *(float4*)(h1 + (size_t)n * HID + fl * 8)     = make_float4(o[0], o[1], o[2], o[3]);
        *(float4*)(h1 + (size_t)n * HID + fl * 8 + 4) = make_float4(o[4], o[5], o[6], o[7]);
    }
}

// ---- layer-2 aggregate + head: wave/node, F=32, bf16 table, int32 sums -------
__global__ __launch_bounds__(256) void agg2_final_kernel(const unsigned short* __restrict__ sorted_src,
                                                         const int* __restrict__ off,
                                                         const unsigned short* __restrict__ len,
                                                         const float* __restrict__ dinv,
                                                         const unsigned short* __restrict__ hws,
                                                         const float* __restrict__ b2,
                                                         const float* __restrict__ Wh,
                                                         const float* __restrict__ bh,
                                                         float* __restrict__ out, int N) {
    int lane = threadIdx.x & 63;
    int n = blockIdx.x * 4 + (threadIdx.x >> 6);
    if (n >= N) return;
    int g = lane >> 2, fl = lane & 3;  // 16 edge-groups x 4 feature-lanes
    int start = off[n], end = start + len[n];
    int acc[8] = {0, 0, 0, 0, 0, 0, 0, 0};
    int i = start + g;
    for (; i + 16 < end; i += 32) {  // 2-way unroll
        int s0 = sorted_src[i], s1 = sorted_src[i + 16];
        uint4 q0 = *(const uint4*)(hws + (size_t)s0 * HID2 + fl * 8);
        uint4 q1 = *(const uint4*)(hws + (size_t)s1 * HID2 + fl * 8);
        acc[0] += (int)bflo(q0.x) + (int)bflo(q1.x);
        acc[1] += (int)bfhi(q0.x) + (int)bfhi(q1.x);
        acc[2] += (int)bflo(q0.y) + (int)bflo(q1.y);
        acc[3] += (int)bfhi(q0.y) + (int)bfhi(q1.y);
        acc[4] += (int)bflo(q0.z) + (int)bflo(q1.z);
        acc[5] += (int)bfhi(q0.z) + (int)bfhi(q1.z);
        acc[6] += (int)bflo(q0.w) + (int)bflo(q1.w);
        acc[7] += (int)bfhi(q0.w) + (int)bfhi(q1.w);
    }
    if (i < end) {
        int s = sorted_src[i];
        uint4 q = *(const uint4*)(hws + (size_t)s * HID2 + fl * 8);
        acc[0] += (int)bflo(q.x); acc[1] += (int)bfhi(q.x);
        acc[2] += (int)bflo(q.y); acc[3] += (int)bfhi(q.y);
        acc[4] += (int)bflo(q.z); acc[5] += (int)bfhi(q.z);
        acc[6] += (int)bflo(q.w); acc[7] += (int)bfhi(q.w);
    }
#pragma unroll
    for (int m = 4; m <= 32; m <<= 1)
#pragma unroll
        for (int j = 0; j < 8; j++) acc[j] += __shfl_xor(acc[j], m, 64);
    float dis = dinv[n] * FPINV;
    uint4 q = *(const uint4*)(hws + (size_t)n * HID2 + fl * 8);
    int sv[8] = {(int)bflo(q.x), (int)bfhi(q.x), (int)bflo(q.y), (int)bfhi(q.y),
                 (int)bflo(q.z), (int)bfhi(q.z), (int)bflo(q.w), (int)bfhi(q.w)};
    float4 bb0 = *(const float4*)(b2 + fl * 8);
    float4 bb1 = *(const float4*)(b2 + fl * 8 + 4);
    float bbv[8] = {bb0.x, bb0.y, bb0.z, bb0.w, bb1.x, bb1.y, bb1.z, bb1.w};
    float4 wv0 = *(const float4*)(Wh + fl * 8);
    float4 wv1 = *(const float4*)(Wh + fl * 8 + 4);
    float wvv[8] = {wv0.x, wv0.y, wv0.z, wv0.w, wv1.x, wv1.y, wv1.z, wv1.w};
    float p = 0.f;
#pragma unroll
    for (int j = 0; j < 8; j++)
        p += fmaxf((float)(acc[j] + sv[j]) * dis + bbv[j], 0.f) * wvv[j];
    p += __shfl_xor(p, 1, 64);
    p += __shfl_xor(p, 2, 64);
    if (lane == 0) out[n] = p + bh[0];
}

extern "C" void kernel_launch(void* const* d_in, const int* in_sizes, int n_in,
                              void* d_out, int out_size, void* d_ws, size_t ws_size,
                              hipStream_t stream) {
    const float* x  = (const float*)d_in[0];
    const int*   ei = (const int*)d_in[1];
    const float* W1 = (const float*)d_in[2];
    const float* b1 = (const float*)d_in[3];
    const float* W2 = (const float*)d_in[4];
    const float* b2 = (const float*)d_in[5];
    const float* Wh = (const float*)d_in[6];
    const float* bh = (const float*)d_in[7];
    float* out = (float*)d_out;

    const int N = N_NODES;
    const int E = in_sizes[1] / 2;
    const int* src = ei;
    const int* dst = ei + E;

    // workspace layout
    int* ws = (int*)d_ws;
    int*            bcur  = ws;                                   // 512 ints
    int*            off   = bcur + 512;                           // 50048 ints
    unsigned short* len   = (unsigned short*)(off + 50048);       // 50048 ushort
    float*          dinv  = (float*)((int*)len + 25024);          // 50048 floats
    unsigned short* psrc  = (unsigned short*)(dinv + 50048);      // NB*CAP ushort (4 MB)
    unsigned char*  pbyte = (unsigned char*)(psrc + (size_t)NB * CAP);  // NB*CAP bytes (2 MB)
    unsigned short* xws   = (unsigned short*)(pbyte + (size_t)NB * CAP);// N*64 bf16 (6.4 MB)
    float*          h1    = (float*)(xws + (size_t)N * HID);      // N*64 f32 (12.8 MB)
    unsigned short* hws   = xws;                                  // alias: xws dead after agg1

    hipMemsetAsync(bcur, 0, NB * sizeof(int), stream);

    int eblocks = (E + CHUNK - 1) / CHUNK;
    bin_kernel<<<eblocks, 256, 0, stream>>>(src, dst, bcur, psrc, pbyte, E);
    fine_kernel<<<NB, 256, 0, stream>>>(psrc, pbyte, bcur, off, len, dinv, N);

    // layer 1
    gemm_s_kernel<IN_CH, HID, 32><<<(N + 31) / 32, 256, 0, stream>>>(x, W1, dinv, xws, N);
    agg1_kernel<<<(N + 3) / 4, 256, 0, stream>>>(psrc, off, len, dinv, xws, b1, h1, N);

    // layer 2 + head
    gemm_s_kernel<HID, HID2, 64><<<(N + 63) / 64, 256, 0, stream>>>(h1, W2, dinv, hws, N);
    agg2_final_kernel<<<(N + 3) / 4, 256, 0, stream>>>(psrc, off, len, dinv, hws, b2, Wh, bh, out, N);
}